// Round 7
// baseline (228.879 us; speedup 1.0000x reference)
//
#include <hip/hip_runtime.h>

// Problem constants
#define BB 2
#define SQ 2048
#define SK 2048
#define DD 1024
#define HH 16
#define HS 64
#define SCALE 0.125f
#define LOG2E 1.4426950408889634f

typedef __bf16 bf16x8 __attribute__((ext_vector_type(8)));
typedef float f32x4 __attribute__((ext_vector_type(4)));
typedef unsigned int uint;

__device__ __forceinline__ void gload_lds16(const __bf16* g, __bf16* l) {
    __builtin_amdgcn_global_load_lds((const __attribute__((address_space(1))) uint*)(g),
                                     (__attribute__((address_space(3))) uint*)(l), 16, 0, 0);
}

// ---------------- cast fp32 -> bf16 (both inputs in one launch) ----------------
__global__ void cast2_f32_bf16(const float* __restrict__ in0, const float* __restrict__ in1,
                               __bf16* __restrict__ out0, __bf16* __restrict__ out1, int n8each) {
    int i = blockIdx.x * blockDim.x + threadIdx.x;
    const float* src;
    __bf16* dst;
    int j;
    if (i < n8each) { src = in0; dst = out0; j = i; }
    else            { src = in1; dst = out1; j = i - n8each; }
    const float4* p = ((const float4*)src) + (size_t)j * 2;
    float4 a = p[0], b = p[1];
    bf16x8 v = {(__bf16)a.x, (__bf16)a.y, (__bf16)a.z, (__bf16)a.w,
                (__bf16)b.x, (__bf16)b.y, (__bf16)b.z, (__bf16)b.w};
    ((bf16x8*)dst)[j] = v;
}

// ------------- cast+transpose the 4 weight matrices [K][N] -> bf16 [N][K] -------------
__global__ void wtrans(const float* __restrict__ W0, const float* __restrict__ W1,
                       const float* __restrict__ W2, const float* __restrict__ W3,
                       __bf16* __restrict__ Wt) {
    __shared__ __bf16 tile[32][33];
    const float* W = blockIdx.z == 0 ? W0 : blockIdx.z == 1 ? W1 : blockIdx.z == 2 ? W2 : W3;
    __bf16* out = Wt + (size_t)blockIdx.z * DD * DD;
    int tx = threadIdx.x, ty = threadIdx.y;     // (32, 8)
    int k0 = blockIdx.y * 32, n0 = blockIdx.x * 32;
#pragma unroll
    for (int j = 0; j < 4; ++j)
        tile[ty + j * 8][tx] = (__bf16)W[(size_t)(k0 + ty + j * 8) * DD + n0 + tx];
    __syncthreads();
#pragma unroll
    for (int j = 0; j < 4; ++j)
        out[(size_t)(n0 + ty + j * 8) * DD + k0 + tx] = tile[tx][ty + j * 8];
}

// ------------- GEMM body: acc = A[4096,1024] @ Bt[1024,1024]^T -------------
// 128x128 tile, BK=64, 256 threads (4 waves, 64x64 quadrant each), global_load_lds staging
// MODE 0: C = bf16 (acc+bias)*scale ; MODE 2: transposed Vt write
#define BM 128
#define BN 128
#define BK 64
template <int MODE>
__device__ __forceinline__ void gemm_body(const __bf16* __restrict__ A, const __bf16* __restrict__ Bt,
                                          const float* __restrict__ bias, void* __restrict__ Cout,
                                          float scale) {
    __shared__ __bf16 As[BM][BK];
    __shared__ __bf16 Bs[BN][BK];
    int t = threadIdx.x;
    int w = t >> 6, l = t & 63;
    int lm = l & 15, lk = l >> 4;
    int wr = w >> 1, wc = w & 1;
    int br = blockIdx.y, bc = blockIdx.x;
    int srow = (l >> 3), scol = (l & 7) * 8;
    f32x4 acc[4][4] = {};
    for (int kt = 0; kt < 1024; kt += BK) {
        __syncthreads();
#pragma unroll
        for (int j = 0; j < 4; ++j) {
            int r0 = (w * 4 + j) * 8;
            gload_lds16(&A[(size_t)(br * BM + r0 + srow) * 1024 + kt + scol], &As[r0][0]);
            gload_lds16(&Bt[(size_t)(bc * BN + r0 + srow) * 1024 + kt + scol], &Bs[r0][0]);
        }
        __syncthreads();
#pragma unroll
        for (int kk = 0; kk < BK; kk += 32) {
            bf16x8 af[4], bf[4];
#pragma unroll
            for (int m = 0; m < 4; ++m) af[m] = *(const bf16x8*)&As[wr * 64 + m * 16 + lm][kk + lk * 8];
#pragma unroll
            for (int n = 0; n < 4; ++n) bf[n] = *(const bf16x8*)&Bs[wc * 64 + n * 16 + lm][kk + lk * 8];
#pragma unroll
            for (int m = 0; m < 4; ++m)
#pragma unroll
                for (int n = 0; n < 4; ++n)
                    acc[m][n] = __builtin_amdgcn_mfma_f32_16x16x32_bf16(af[m], bf[n], acc[m][n], 0, 0, 0);
        }
    }
#pragma unroll
    for (int m = 0; m < 4; ++m)
#pragma unroll
        for (int n = 0; n < 4; ++n) {
            int col = bc * BN + wc * 64 + n * 16 + lm;
            float bv = bias[col];
            if constexpr (MODE == 2) {
                // Vt[((b*16+h)*64+d)*2048 + sk], sk = global row; 4 accs are 4 consecutive sk
                int row = br * BM + wr * 64 + m * 16 + lk * 4;   // sk0 (multiple of 4)
                int b_ = row >> 11, sk = row & 2047;
                int h_ = col >> 6, d_ = col & 63;
                union { ushort4 u; __bf16 h[4]; } pk;
#pragma unroll
                for (int r = 0; r < 4; ++r) pk.h[r] = (__bf16)(acc[m][n][r] + bv);
                *(ushort4*)((__bf16*)Cout + ((size_t)((b_ * 16 + h_) * 64 + d_) * 2048 + sk)) = pk.u;
            } else {
#pragma unroll
                for (int r = 0; r < 4; ++r) {
                    int row = br * BM + wr * 64 + m * 16 + lk * 4 + r;
                    ((__bf16*)Cout)[(size_t)row * 1024 + col] = (__bf16)((acc[m][n][r] + bv) * scale);
                }
            }
        }
}

// fused Q/K/V projections: z==0 -> Q (scaled), z==1 -> K, z==2 -> V written transposed as Vt
__global__ __launch_bounds__(256) void gemm_qkv(const __bf16* __restrict__ Ain, const __bf16* __restrict__ Actx,
                                                const __bf16* __restrict__ Wt,
                                                const float* __restrict__ bq, const float* __restrict__ bk,
                                                const float* __restrict__ bv,
                                                __bf16* __restrict__ Qb, __bf16* __restrict__ Kb,
                                                __bf16* __restrict__ Vtb, float qscale) {
    int z = blockIdx.z;
    const __bf16* A = (z == 0) ? Ain : Actx;
    const __bf16* B = Wt + (size_t)z * DD * DD;
    if (z == 0)      gemm_body<0>(A, B, bq, Qb, qscale);
    else if (z == 1) gemm_body<0>(A, B, bk, Kb, 1.f);
    else             gemm_body<2>(A, B, bv, Vtb, 1.f);
}

// ------------- output GEMM: 64x128 tile (grid 512 = 2 blocks/CU), float out -------------
__global__ __launch_bounds__(256) void gemm_out64(const __bf16* __restrict__ A, const __bf16* __restrict__ Bt,
                                                  const float* __restrict__ bias, float* __restrict__ C) {
    __shared__ __bf16 As[64][64];
    __shared__ __bf16 Bs[128][64];
    int t = threadIdx.x;
    int w = t >> 6, l = t & 63;
    int lm = l & 15, lk = l >> 4;
    int br = blockIdx.y, bc = blockIdx.x;   // grid (8, 64)
    int srow = (l >> 3), scol = (l & 7) * 8;
    f32x4 acc[4][2] = {};
    for (int kt = 0; kt < 1024; kt += 64) {
        __syncthreads();
#pragma unroll
        for (int j = 0; j < 2; ++j) {
            int r0 = (j * 4 + w) * 8;
            gload_lds16(&A[(size_t)(br * 64 + r0 + srow) * 1024 + kt + scol], &As[r0][0]);
        }
#pragma unroll
        for (int j = 0; j < 4; ++j) {
            int r0 = (j * 4 + w) * 8;
            gload_lds16(&Bt[(size_t)(bc * 128 + r0 + srow) * 1024 + kt + scol], &Bs[r0][0]);
        }
        __syncthreads();
#pragma unroll
        for (int kk = 0; kk < 64; kk += 32) {
            bf16x8 af[4], bf[2];
#pragma unroll
            for (int m = 0; m < 4; ++m) af[m] = *(const bf16x8*)&As[m * 16 + lm][kk + lk * 8];
#pragma unroll
            for (int n = 0; n < 2; ++n) bf[n] = *(const bf16x8*)&Bs[w * 32 + n * 16 + lm][kk + lk * 8];
#pragma unroll
            for (int m = 0; m < 4; ++m)
#pragma unroll
                for (int n = 0; n < 2; ++n)
                    acc[m][n] = __builtin_amdgcn_mfma_f32_16x16x32_bf16(af[m], bf[n], acc[m][n], 0, 0, 0);
        }
    }
#pragma unroll
    for (int m = 0; m < 4; ++m)
#pragma unroll
        for (int n = 0; n < 2; ++n) {
            int col = bc * 128 + w * 32 + n * 16 + lm;
            float bv = bias[col];
#pragma unroll
            for (int r = 0; r < 4; ++r) {
                int row = br * 64 + m * 16 + lk * 4 + r;
                C[(size_t)row * 1024 + col] = acc[m][n][r] + bv;
            }
        }
}

// ------------- flash attention, swapped-QK^T (S^T), lane-local P -------------
// QBLK=128: 4 waves x 32 q-rows; KVBLK=64.
// K: double-buffered LDS via global_load_lds (linear dest, inverse-swizzled SOURCE column,
//    swizzled read -- same involution; rule 21). One barrier per tile drains it.
// V: read DIRECT from L2-resident Vt (no LDS): vf[dn] elem j needs kv = kv0+32kk+16(j>>2)+4lk+(j&3)
//    -> two contiguous 8B loads per (dn,kk). L1 absorbs cross-wave redundancy.
// Row-sums: extra MFMA with all-ones B (o_s) -- lands sums at exactly the epilogue lanes.
__global__ __launch_bounds__(256) void flash_attn(const __bf16* __restrict__ Q,
                                                  const __bf16* __restrict__ Kb,
                                                  const __bf16* __restrict__ Vt,
                                                  __bf16* __restrict__ O) {
    __shared__ __bf16 Ks[2][64 * 64];
    int t = threadIdx.x, w = t >> 6, l = t & 63;
    int lm = l & 15, lk = l >> 4;
    int bh = blockIdx.y, b = bh >> 4, h = bh & 15;
    int q0 = blockIdx.x * 128;

    // Q fragments straight from global (one-time): wave w owns q rows q0+w*32 .. +31
    bf16x8 qf[2][2];
#pragma unroll
    for (int m = 0; m < 2; ++m)
#pragma unroll
        for (int kk = 0; kk < 2; ++kk)
            qf[m][kk] = *(const bf16x8*)&Q[(size_t)(b * SQ + q0 + w * 32 + m * 16 + lm) * DD + h * HS + kk * 32 + lk * 8];

    // K staging geometry: lane covers rows r0, r0+32; chunk c8; source column pre-swizzled
    int r0 = t >> 3, c8 = t & 7;
    int c8s = c8 ^ (r0 & 7);
    const __bf16* kbase = Kb + (size_t)b * SK * DD + h * HS;
    const __bf16* vbase = Vt + (size_t)bh * HS * SK;

#define K_STAGE(BUF, KV)                                                               \
    gload_lds16(&kbase[(size_t)((KV) + r0) * DD + c8s * 8], &Ks[BUF][w * 512]);        \
    gload_lds16(&kbase[(size_t)((KV) + r0 + 32) * DD + c8s * 8], &Ks[BUF][w * 512 + 2048]);

    K_STAGE(0, 0);
    __syncthreads();

    bf16x8 ones;
#pragma unroll
    for (int j = 0; j < 8; ++j) ones[j] = (__bf16)1.0f;

    f32x4 o[2][4] = {};
    f32x4 o_s[2] = {};

    for (int it = 0; it < 32; ++it) {
        int buf = it & 1;
        int kv0 = it * 64;
        if (it + 1 < 32) { K_STAGE(buf ^ 1, kv0 + 64); }   // in flight across the tile

        const __bf16* KsB = &Ks[buf][0];

        // S^T = K Q^T : st[n][m], lane holds P[q=m*16+lm][kv=16n+4lk+r]
        f32x4 st[4][2] = {};
        __builtin_amdgcn_s_setprio(1);
#pragma unroll
        for (int kk = 0; kk < 2; ++kk) {
            bf16x8 kf[4];
#pragma unroll
            for (int n = 0; n < 4; ++n)
                kf[n] = *(const bf16x8*)&KsB[(n * 16 + lm) * 64 + (((kk * 4 + lk) ^ (lm & 7)) * 8)];
#pragma unroll
            for (int n = 0; n < 4; ++n)
#pragma unroll
                for (int m = 0; m < 2; ++m)
                    st[n][m] = __builtin_amdgcn_mfma_f32_16x16x32_bf16(kf[n], qf[m][kk], st[n][m], 0, 0, 0);
        }
        __builtin_amdgcn_s_setprio(0);

        // P = exp2(S); PV + ones-column row-sum, V direct from global
#pragma unroll
        for (int kk = 0; kk < 2; ++kk) {
            bf16x8 pa[2];
#pragma unroll
            for (int m = 0; m < 2; ++m)
#pragma unroll
                for (int j = 0; j < 8; ++j)
                    pa[m][j] = (__bf16)exp2f(st[2 * kk + (j >> 2)][m][j & 3]);
            __builtin_amdgcn_s_setprio(1);
#pragma unroll
            for (int m = 0; m < 2; ++m)
                o_s[m] = __builtin_amdgcn_mfma_f32_16x16x32_bf16(pa[m], ones, o_s[m], 0, 0, 0);
#pragma unroll
            for (int dn = 0; dn < 4; ++dn) {
                const __bf16* vrow = vbase + (size_t)(dn * 16 + lm) * SK + kv0 + kk * 32 + lk * 4;
                union { float2 f2; __bf16 h[4]; } vlo, vhi;
                vlo.f2 = *(const float2*)vrow;
                vhi.f2 = *(const float2*)(vrow + 16);
                bf16x8 vf = {vlo.h[0], vlo.h[1], vlo.h[2], vlo.h[3],
                             vhi.h[0], vhi.h[1], vhi.h[2], vhi.h[3]};
#pragma unroll
                for (int m = 0; m < 2; ++m)
                    o[m][dn] = __builtin_amdgcn_mfma_f32_16x16x32_bf16(pa[m], vf, o[m][dn], 0, 0, 0);
            }
            __builtin_amdgcn_s_setprio(0);
        }

        __syncthreads();   // waves done reading Ks[buf]; drains K_STAGE into buf^1
    }

    // epilogue: o_s[m][r] already holds rowsum(q = m*16 + lk*4 + r) at every lm lane
#pragma unroll
    for (int m = 0; m < 2; ++m) {
        f32x4 inv;
#pragma unroll
        for (int r = 0; r < 4; ++r) inv[r] = 1.f / o_s[m][r];
#pragma unroll
        for (int dn = 0; dn < 4; ++dn)
#pragma unroll
            for (int r = 0; r < 4; ++r) {
                int row = q0 + w * 32 + m * 16 + lk * 4 + r;
                int col = h * HS + dn * 16 + lm;
                O[(size_t)(b * SQ + row) * DD + col] = (__bf16)(o[m][dn][r] * inv[r]);
            }
    }
}

extern "C" void kernel_launch(void* const* d_in, const int* in_sizes, int n_in,
                              void* d_out, int out_size, void* d_ws, size_t ws_size,
                              hipStream_t stream) {
    const float* inputs  = (const float*)d_in[0];
    const float* context = (const float*)d_in[1];
    const float* Wq = (const float*)d_in[2];
    const float* bq = (const float*)d_in[3];
    const float* Wk = (const float*)d_in[4];
    const float* bk = (const float*)d_in[5];
    const float* Wv = (const float*)d_in[6];
    const float* bv = (const float*)d_in[7];
    const float* Wo = (const float*)d_in[8];
    const float* bo = (const float*)d_in[9];
    float* out = (float*)d_out;

    char* ws = (char*)d_ws;
    const size_t SEG = (size_t)4096 * 1024 * sizeof(__bf16);  // 8 MB
    __bf16* inA  = (__bf16*)(ws + 0 * SEG);
    __bf16* ctxB = (__bf16*)(ws + 1 * SEG);
    __bf16* Wt   = (__bf16*)(ws + 2 * SEG);   // 4 x 1024x1024 bf16
    __bf16* Qb   = (__bf16*)(ws + 3 * SEG);
    __bf16* Kbuf = (__bf16*)(ws + 4 * SEG);
    __bf16* Vtb  = (__bf16*)(ws + 5 * SEG);   // V written directly transposed by gemm_qkv
    __bf16* attb = ctxB;                      // context_bf16 dead after QKV GEMM

    int n8 = 4096 * 1024 / 8;
    cast2_f32_bf16<<<2 * n8 / 256, 256, 0, stream>>>(inputs, context, inA, ctxB, n8);
    wtrans<<<dim3(32, 32, 4), dim3(32, 8), 0, stream>>>(Wq, Wk, Wv, Wo, Wt);

    gemm_qkv<<<dim3(8, 32, 3), 256, 0, stream>>>(inA, ctxB, Wt, bq, bk, bv,
                                                 Qb, Kbuf, Vtb, SCALE * LOG2E);

    flash_attn<<<dim3(16, 32), 256, 0, stream>>>(Qb, Kbuf, Vtb, attb);

    gemm_out64<<<dim3(8, 64), 256, 0, stream>>>(attb, Wt + (size_t)3 * DD * DD, bo, out);
}

// Round 8
// 146.172 us; speedup vs baseline: 1.5658x; 1.5658x over previous
//
#include <hip/hip_runtime.h>

// Problem constants
#define BB 2
#define SQ 2048
#define SK 2048
#define DD 1024
#define HH 16
#define HS 64
#define SCALE 0.125f
#define LOG2E 1.4426950408889634f

typedef __bf16 bf16x8 __attribute__((ext_vector_type(8)));
typedef float f32x4 __attribute__((ext_vector_type(4)));
typedef unsigned int uint;

__device__ __forceinline__ void gload_lds16(const __bf16* g, __bf16* l) {
    __builtin_amdgcn_global_load_lds((const __attribute__((address_space(1))) uint*)(g),
                                     (__attribute__((address_space(3))) uint*)(l), 16, 0, 0);
}

// ---------------- cast fp32 -> bf16 (both inputs in one launch) ----------------
__global__ void cast2_f32_bf16(const float* __restrict__ in0, const float* __restrict__ in1,
                               __bf16* __restrict__ out0, __bf16* __restrict__ out1, int n8each) {
    int i = blockIdx.x * blockDim.x + threadIdx.x;
    const float* src;
    __bf16* dst;
    int j;
    if (i < n8each) { src = in0; dst = out0; j = i; }
    else            { src = in1; dst = out1; j = i - n8each; }
    const float4* p = ((const float4*)src) + (size_t)j * 2;
    float4 a = p[0], b = p[1];
    bf16x8 v = {(__bf16)a.x, (__bf16)a.y, (__bf16)a.z, (__bf16)a.w,
                (__bf16)b.x, (__bf16)b.y, (__bf16)b.z, (__bf16)b.w};
    ((bf16x8*)dst)[j] = v;
}

// ------------- cast+transpose the 4 weight matrices [K][N] -> bf16 [N][K] -------------
__global__ void wtrans(const float* __restrict__ W0, const float* __restrict__ W1,
                       const float* __restrict__ W2, const float* __restrict__ W3,
                       __bf16* __restrict__ Wt) {
    __shared__ __bf16 tile[32][33];
    const float* W = blockIdx.z == 0 ? W0 : blockIdx.z == 1 ? W1 : blockIdx.z == 2 ? W2 : W3;
    __bf16* out = Wt + (size_t)blockIdx.z * DD * DD;
    int tx = threadIdx.x, ty = threadIdx.y;     // (32, 8)
    int k0 = blockIdx.y * 32, n0 = blockIdx.x * 32;
#pragma unroll
    for (int j = 0; j < 4; ++j)
        tile[ty + j * 8][tx] = (__bf16)W[(size_t)(k0 + ty + j * 8) * DD + n0 + tx];
    __syncthreads();
#pragma unroll
    for (int j = 0; j < 4; ++j)
        out[(size_t)(n0 + ty + j * 8) * DD + k0 + tx] = tile[tx][ty + j * 8];
}

// ------------- GEMM body: acc = A[4096,1024] @ Bt[1024,1024]^T -------------
// 128x128 tile, BK=64, 256 threads (4 waves, 64x64 quadrant each), global_load_lds staging
// MODE 0: C = bf16 (acc+bias)*scale ; MODE 2: transposed + kv-bit-permuted Vt write
#define BM 128
#define BN 128
#define BK 64
template <int MODE>
__device__ __forceinline__ void gemm_body(const __bf16* __restrict__ A, const __bf16* __restrict__ Bt,
                                          const float* __restrict__ bias, void* __restrict__ Cout,
                                          float scale) {
    __shared__ __bf16 As[BM][BK];
    __shared__ __bf16 Bs[BN][BK];
    int t = threadIdx.x;
    int w = t >> 6, l = t & 63;
    int lm = l & 15, lk = l >> 4;
    int wr = w >> 1, wc = w & 1;
    int br = blockIdx.y, bc = blockIdx.x;
    int srow = (l >> 3), scol = (l & 7) * 8;
    f32x4 acc[4][4] = {};
    for (int kt = 0; kt < 1024; kt += BK) {
        __syncthreads();
#pragma unroll
        for (int j = 0; j < 4; ++j) {
            int r0 = (w * 4 + j) * 8;
            gload_lds16(&A[(size_t)(br * BM + r0 + srow) * 1024 + kt + scol], &As[r0][0]);
            gload_lds16(&Bt[(size_t)(bc * BN + r0 + srow) * 1024 + kt + scol], &Bs[r0][0]);
        }
        __syncthreads();
#pragma unroll
        for (int kk = 0; kk < BK; kk += 32) {
            bf16x8 af[4], bf[4];
#pragma unroll
            for (int m = 0; m < 4; ++m) af[m] = *(const bf16x8*)&As[wr * 64 + m * 16 + lm][kk + lk * 8];
#pragma unroll
            for (int n = 0; n < 4; ++n) bf[n] = *(const bf16x8*)&Bs[wc * 64 + n * 16 + lm][kk + lk * 8];
#pragma unroll
            for (int m = 0; m < 4; ++m)
#pragma unroll
                for (int n = 0; n < 4; ++n)
                    acc[m][n] = __builtin_amdgcn_mfma_f32_16x16x32_bf16(af[m], bf[n], acc[m][n], 0, 0, 0);
        }
    }
#pragma unroll
    for (int m = 0; m < 4; ++m)
#pragma unroll
        for (int n = 0; n < 4; ++n) {
            int col = bc * BN + wc * 64 + n * 16 + lm;
            float bv = bias[col];
            if constexpr (MODE == 2) {
                // Vt value for key-pos sk stored at sigma-permuted position:
                // within 64-block: p = o5<<5 | o3<<4 | o2<<3 | o4<<2 | o1o0  (o = sk & 63)
                // (sigma from round-6's verified in-LDS permutation; r-quad stays contiguous)
                int row = br * BM + wr * 64 + m * 16 + lk * 4;   // sk0 (multiple of 4)
                int b_ = row >> 11, sk = row & 2047;
                int skb = sk & ~63, o = sk & 63;
                int p0 = (o & 32) | (((o >> 3) & 1) << 4) | (((o >> 2) & 1) << 3) | (((o >> 4) & 1) << 2);
                int h_ = col >> 6, d_ = col & 63;
                union { ushort4 u; __bf16 h[4]; } pk;
#pragma unroll
                for (int r = 0; r < 4; ++r) pk.h[r] = (__bf16)(acc[m][n][r] + bv);
                *(ushort4*)((__bf16*)Cout + ((size_t)((b_ * 16 + h_) * 64 + d_) * 2048 + skb + p0)) = pk.u;
            } else {
#pragma unroll
                for (int r = 0; r < 4; ++r) {
                    int row = br * BM + wr * 64 + m * 16 + lk * 4 + r;
                    ((__bf16*)Cout)[(size_t)row * 1024 + col] = (__bf16)((acc[m][n][r] + bv) * scale);
                }
            }
        }
}

// fused Q/K/V projections: z==0 -> Q (scaled), z==1 -> K, z==2 -> V written transposed+permuted as Vt
__global__ __launch_bounds__(256) void gemm_qkv(const __bf16* __restrict__ Ain, const __bf16* __restrict__ Actx,
                                                const __bf16* __restrict__ Wt,
                                                const float* __restrict__ bq, const float* __restrict__ bk,
                                                const float* __restrict__ bv,
                                                __bf16* __restrict__ Qb, __bf16* __restrict__ Kb,
                                                __bf16* __restrict__ Vtb, float qscale) {
    int z = blockIdx.z;
    const __bf16* A = (z == 0) ? Ain : Actx;
    const __bf16* B = Wt + (size_t)z * DD * DD;
    if (z == 0)      gemm_body<0>(A, B, bq, Qb, qscale);
    else if (z == 1) gemm_body<0>(A, B, bk, Kb, 1.f);
    else             gemm_body<2>(A, B, bv, Vtb, 1.f);
}

// ------------- output GEMM: 64x128 tile (grid 512 = 2 blocks/CU), float out -------------
__global__ __launch_bounds__(256) void gemm_out64(const __bf16* __restrict__ A, const __bf16* __restrict__ Bt,
                                                  const float* __restrict__ bias, float* __restrict__ C) {
    __shared__ __bf16 As[64][64];
    __shared__ __bf16 Bs[128][64];
    int t = threadIdx.x;
    int w = t >> 6, l = t & 63;
    int lm = l & 15, lk = l >> 4;
    int br = blockIdx.y, bc = blockIdx.x;   // grid (8, 64)
    int srow = (l >> 3), scol = (l & 7) * 8;
    f32x4 acc[4][2] = {};
    for (int kt = 0; kt < 1024; kt += 64) {
        __syncthreads();
#pragma unroll
        for (int j = 0; j < 2; ++j) {
            int r0 = (j * 4 + w) * 8;
            gload_lds16(&A[(size_t)(br * 64 + r0 + srow) * 1024 + kt + scol], &As[r0][0]);
        }
#pragma unroll
        for (int j = 0; j < 4; ++j) {
            int r0 = (j * 4 + w) * 8;
            gload_lds16(&Bt[(size_t)(bc * 128 + r0 + srow) * 1024 + kt + scol], &Bs[r0][0]);
        }
        __syncthreads();
#pragma unroll
        for (int kk = 0; kk < 64; kk += 32) {
            bf16x8 af[4], bf[2];
#pragma unroll
            for (int m = 0; m < 4; ++m) af[m] = *(const bf16x8*)&As[m * 16 + lm][kk + lk * 8];
#pragma unroll
            for (int n = 0; n < 2; ++n) bf[n] = *(const bf16x8*)&Bs[w * 32 + n * 16 + lm][kk + lk * 8];
#pragma unroll
            for (int m = 0; m < 4; ++m)
#pragma unroll
                for (int n = 0; n < 2; ++n)
                    acc[m][n] = __builtin_amdgcn_mfma_f32_16x16x32_bf16(af[m], bf[n], acc[m][n], 0, 0, 0);
        }
    }
#pragma unroll
    for (int m = 0; m < 4; ++m)
#pragma unroll
        for (int n = 0; n < 2; ++n) {
            int col = bc * 128 + w * 32 + n * 16 + lm;
            float bv = bias[col];
#pragma unroll
            for (int r = 0; r < 4; ++r) {
                int row = br * 64 + m * 16 + lk * 4 + r;
                C[(size_t)row * 1024 + col] = acc[m][n][r] + bv;
            }
        }
}

// ------------- flash attention, swapped-QK^T (S^T), lane-local P -------------
// QBLK=128: 4 waves x 32 q-rows; KVBLK=64, double-buffered K/V, 1 barrier/tile.
// V's kv-permutation sigma is baked into Vt's GLOBAL layout (gemm_qkv MODE 2), so K and V
// staging are identical: reg load-early (T14), XOR-swizzled float4 LDS store after compute.
// Row-sums via extra MFMA against all-ones B (lands at exactly the epilogue lanes).
__global__ __launch_bounds__(256) void flash_attn(const __bf16* __restrict__ Q,
                                                  const __bf16* __restrict__ Kb,
                                                  const __bf16* __restrict__ Vt,
                                                  __bf16* __restrict__ O) {
    __shared__ __bf16 Ks[2][64 * 64];
    __shared__ __bf16 Vs[2][64 * 64];
    int t = threadIdx.x, w = t >> 6, l = t & 63;
    int lm = l & 15, lk = l >> 4;
    int bh = blockIdx.y, b = bh >> 4, h = bh & 15;
    int q0 = blockIdx.x * 128;

    // Q fragments straight from global (one-time): wave w owns q rows q0+w*32 .. +31
    bf16x8 qf[2][2];
#pragma unroll
    for (int m = 0; m < 2; ++m)
#pragma unroll
        for (int kk = 0; kk < 2; ++kk)
            qf[m][kk] = *(const bf16x8*)&Q[(size_t)(b * SQ + q0 + w * 32 + m * 16 + lm) * DD + h * HS + kk * 32 + lk * 8];

    // staging geometry: thread covers rows r0 and r0+32, 8-elem chunk c8; swizzled chunk c8^(r0&7)
    int r0 = t >> 3, c8 = t & 7;
    int chs = c8 ^ (r0 & 7);
    const __bf16* kbase = Kb + (size_t)b * SK * DD + h * HS;      // + (kv+row)*DD + c8*8
    const __bf16* vbase = Vt + (size_t)bh * HS * SK;              // + d*SK + kv + c8*8 (pre-permuted)
    __bf16* ksl0 = &Ks[0][(r0)      * 64 + chs * 8];
    __bf16* ksl1 = &Ks[0][(r0 + 32) * 64 + chs * 8];
    __bf16* vsl0 = &Vs[0][(r0)      * 64 + chs * 8];
    __bf16* vsl1 = &Vs[0][(r0 + 32) * 64 + chs * 8];

    float4 kr0, kr1, vr0, vr1;   // NAMED regs only (arrays -> scratch)
#define FA_LOAD(KV)                                                              \
    kr0 = *(const float4*)&kbase[(size_t)((KV) + r0) * DD + c8 * 8];             \
    kr1 = *(const float4*)&kbase[(size_t)((KV) + r0 + 32) * DD + c8 * 8];        \
    vr0 = *(const float4*)&vbase[(size_t)(r0) * SK + (KV) + c8 * 8];             \
    vr1 = *(const float4*)&vbase[(size_t)(r0 + 32) * SK + (KV) + c8 * 8];
#define FA_WRITE(BUF)                                                            \
    *(float4*)(ksl0 + (BUF) * 4096) = kr0;                                       \
    *(float4*)(ksl1 + (BUF) * 4096) = kr1;                                       \
    *(float4*)(vsl0 + (BUF) * 4096) = vr0;                                       \
    *(float4*)(vsl1 + (BUF) * 4096) = vr1;

    FA_LOAD(0);
    FA_WRITE(0);
    __syncthreads();

    bf16x8 ones;
#pragma unroll
    for (int j = 0; j < 8; ++j) ones[j] = (__bf16)1.0f;

    f32x4 o[2][4] = {};
    f32x4 o_s[2] = {};

    for (int it = 0; it < 32; ++it) {
        int buf = it & 1;
        if (it + 1 < 32) { FA_LOAD((it + 1) * 64); }   // issue early; hides under compute

        const __bf16* KsB = &Ks[buf][0];
        const __bf16* VsB = &Vs[buf][0];

        // S^T = K Q^T : st[n][m], lane holds P[q=m*16+lm][kv=16n+4lk+r]
        f32x4 st[4][2] = {};
        __builtin_amdgcn_s_setprio(1);
#pragma unroll
        for (int kk = 0; kk < 2; ++kk) {
            bf16x8 kf[4];
#pragma unroll
            for (int n = 0; n < 4; ++n)
                kf[n] = *(const bf16x8*)&KsB[(n * 16 + lm) * 64 + (((kk * 4 + lk) ^ (lm & 7)) * 8)];
#pragma unroll
            for (int n = 0; n < 4; ++n)
#pragma unroll
                for (int m = 0; m < 2; ++m)
                    st[n][m] = __builtin_amdgcn_mfma_f32_16x16x32_bf16(kf[n], qf[m][kk], st[n][m], 0, 0, 0);
        }
        __builtin_amdgcn_s_setprio(0);

        // P = exp2(S) fused into fragment assembly; PV + ones-column row-sum
#pragma unroll
        for (int kk = 0; kk < 2; ++kk) {
            bf16x8 pa[2], vf[4];
#pragma unroll
            for (int m = 0; m < 2; ++m)
#pragma unroll
                for (int j = 0; j < 8; ++j)
                    pa[m][j] = (__bf16)exp2f(st[2 * kk + (j >> 2)][m][j & 3]);
#pragma unroll
            for (int dn = 0; dn < 4; ++dn)
                vf[dn] = *(const bf16x8*)&VsB[(dn * 16 + lm) * 64 + (((kk * 4 + lk) ^ (lm & 7)) * 8)];
            __builtin_amdgcn_s_setprio(1);
#pragma unroll
            for (int m = 0; m < 2; ++m)
                o_s[m] = __builtin_amdgcn_mfma_f32_16x16x32_bf16(pa[m], ones, o_s[m], 0, 0, 0);
#pragma unroll
            for (int m = 0; m < 2; ++m)
#pragma unroll
                for (int dn = 0; dn < 4; ++dn)
                    o[m][dn] = __builtin_amdgcn_mfma_f32_16x16x32_bf16(pa[m], vf[dn], o[m][dn], 0, 0, 0);
            __builtin_amdgcn_s_setprio(0);
        }

        if (it + 1 < 32) { FA_WRITE(buf ^ 1); }        // lands in the other buffer
        __syncthreads();                               // one barrier per tile
    }

    // epilogue: o_s[m][r] holds rowsum(q = m*16 + lk*4 + r) at every lm lane
#pragma unroll
    for (int m = 0; m < 2; ++m) {
        f32x4 inv;
#pragma unroll
        for (int r = 0; r < 4; ++r) inv[r] = 1.f / o_s[m][r];
#pragma unroll
        for (int dn = 0; dn < 4; ++dn)
#pragma unroll
            for (int r = 0; r < 4; ++r) {
                int row = q0 + w * 32 + m * 16 + lk * 4 + r;
                int col = h * HS + dn * 16 + lm;
                O[(size_t)(b * SQ + row) * DD + col] = (__bf16)(o[m][dn][r] * inv[r]);
            }
    }
}

extern "C" void kernel_launch(void* const* d_in, const int* in_sizes, int n_in,
                              void* d_out, int out_size, void* d_ws, size_t ws_size,
                              hipStream_t stream) {
    const float* inputs  = (const float*)d_in[0];
    const float* context = (const float*)d_in[1];
    const float* Wq = (const float*)d_in[2];
    const float* bq = (const float*)d_in[3];
    const float* Wk = (const float*)d_in[4];
    const float* bk = (const float*)d_in[5];
    const float* Wv = (const float*)d_in[6];
    const float* bv = (const float*)d_in[7];
    const float* Wo = (const float*)d_in[8];
    const float* bo = (const float*)d_in[9];
    float* out = (float*)d_out;

    char* ws = (char*)d_ws;
    const size_t SEG = (size_t)4096 * 1024 * sizeof(__bf16);  // 8 MB
    __bf16* inA  = (__bf16*)(ws + 0 * SEG);
    __bf16* ctxB = (__bf16*)(ws + 1 * SEG);
    __bf16* Wt   = (__bf16*)(ws + 2 * SEG);   // 4 x 1024x1024 bf16
    __bf16* Qb   = (__bf16*)(ws + 3 * SEG);
    __bf16* Kbuf = (__bf16*)(ws + 4 * SEG);
    __bf16* Vtb  = (__bf16*)(ws + 5 * SEG);   // V transposed + sigma-permuted by gemm_qkv
    __bf16* attb = ctxB;                      // context_bf16 dead after QKV GEMM

    int n8 = 4096 * 1024 / 8;
    cast2_f32_bf16<<<2 * n8 / 256, 256, 0, stream>>>(inputs, context, inA, ctxB, n8);
    wtrans<<<dim3(32, 32, 4), dim3(32, 8), 0, stream>>>(Wq, Wk, Wv, Wo, Wt);

    gemm_qkv<<<dim3(8, 32, 3), 256, 0, stream>>>(inA, ctxB, Wt, bq, bk, bv,
                                                 Qb, Kbuf, Vtb, SCALE * LOG2E);

    flash_attn<<<dim3(16, 32), 256, 0, stream>>>(Qb, Kbuf, Vtb, attb);

    gemm_out64<<<dim3(8, 64), 256, 0, stream>>>(attb, Wt + (size_t)3 * DD * DD, bo, out);
}